// Round 6
// baseline (301.790 us; speedup 1.0000x reference)
//
#include <hip/hip_runtime.h>
#include <hip/hip_bf16.h>

#define N_TOK 8192
#define N_EXP 8
#define DIM_IN 2048
#define DIM_OUT 2048

#define BM 256
#define BN 256
#define BK 64
#define NKT (DIM_IN / BK)   // 32 K-tiles

#define NX_ELEMS (N_TOK * DIM_IN)              // 16,777,216
#define NW_ELEMS (N_EXP * DIM_OUT * DIM_IN)    // 33,554,432

typedef __attribute__((ext_vector_type(8))) short bf16x8_t;
typedef __attribute__((ext_vector_type(8))) short s16x8_t;
typedef __attribute__((ext_vector_type(4))) short s16x4_t;
typedef __attribute__((ext_vector_type(4))) float f32x4_t;

__device__ __forceinline__ short f2bf(float f) {
    union { __hip_bfloat16 h; short s; } u;
    u.h = __float2bfloat16(f);
    return u.s;
}

__device__ __forceinline__ float bf2f(unsigned short s) {
    union { float f; unsigned u; } v;
    v.u = ((unsigned)s) << 16;
    return v.f;
}

__device__ __forceinline__ void gload_lds16(const void* g, void* l) {
    __builtin_amdgcn_global_load_lds(
        (const __attribute__((address_space(1))) void*)g,
        (__attribute__((address_space(3))) void*)l, 16, 0, 0);
}

// ---------------------------------------------------------------- zero kernel
__global__ void moe_zero_kernel(float4* __restrict__ y, int n4, int* __restrict__ counts) {
    int i = blockIdx.x * blockDim.x + threadIdx.x;
    if (i < N_EXP) counts[i] = 0;
    float4 z; z.x = 0.f; z.y = 0.f; z.z = 0.f; z.w = 0.f;
    for (; i < n4; i += gridDim.x * blockDim.x) y[i] = z;
}

// ---------------------------------------------------------------- f32 -> bf16 convert (X then W) + fused 8-way scan
__global__ void moe_cvt_kernel(const float* __restrict__ X, const float* __restrict__ W,
                               unsigned short* __restrict__ Xb, unsigned short* __restrict__ Wb,
                               const int* __restrict__ counts, int* __restrict__ base) {
    if (blockIdx.x == 0 && threadIdx.x == 0) {
        int s = 0;
#pragma unroll
        for (int e = 0; e < N_EXP; ++e) { base[e] = s; s += counts[e]; }
        base[N_EXP] = s;
    }
    const long long total8 = (long long)(NX_ELEMS + NW_ELEMS) / 8;
    for (long long i = blockIdx.x * blockDim.x + threadIdx.x; i < total8;
         i += (long long)gridDim.x * blockDim.x) {
        long long b8 = i * 8;
        const float* src;
        unsigned short* dst;
        if (b8 < NX_ELEMS) { src = X + b8; dst = Xb + b8; }
        else { src = W + (b8 - NX_ELEMS); dst = Wb + (b8 - NX_ELEMS); }
        // nontemporal: f32 inputs are never re-read; keep LLC for Xb/Wb/scratch.
        f32x4_t a = __builtin_nontemporal_load((const f32x4_t*)src);
        f32x4_t b = __builtin_nontemporal_load((const f32x4_t*)(src + 4));
        s16x8_t h;
        h[0] = f2bf(a[0]); h[1] = f2bf(a[1]); h[2] = f2bf(a[2]); h[3] = f2bf(a[3]);
        h[4] = f2bf(b[0]); h[5] = f2bf(b[1]); h[6] = f2bf(b[2]); h[7] = f2bf(b[3]);
        *(s16x8_t*)dst = h;
    }
}

// ---------------------------------------------------------------- gating
__global__ void moe_gate_kernel(const float* __restrict__ G,
                                int* __restrict__ counts,
                                int* __restrict__ lists,
                                float* __restrict__ lw,
                                int* __restrict__ slotA, int* __restrict__ slotB,
                                float* __restrict__ wAo, float* __restrict__ wBo) {
    int t = blockIdx.x * blockDim.x + threadIdx.x;
    if (t >= N_TOK) return;
    float g[N_EXP];
#pragma unroll
    for (int e = 0; e < N_EXP; ++e) g[e] = G[t * N_EXP + e];
    int i0 = 0; float b0 = g[0];
#pragma unroll
    for (int e = 1; e < N_EXP; ++e) if (g[e] > b0) { b0 = g[e]; i0 = e; }
    int i1 = -1; float b1 = -INFINITY;
#pragma unroll
    for (int e = 0; e < N_EXP; ++e) if (e != i0 && g[e] > b1) { b1 = g[e]; i1 = e; }
    float e1 = expf(b1 - b0);
    float w0 = 1.0f / (1.0f + e1);
    float w1 = e1 * w0;
    int p0 = atomicAdd(&counts[i0], 1);
    lists[i0 * N_TOK + p0] = t;
    lw[i0 * N_TOK + p0] = w0;
    int p1 = atomicAdd(&counts[i1], 1);
    lists[i1 * N_TOK + p1] = t;
    lw[i1 * N_TOK + p1] = w1;
    slotA[t] = (i0 << 13) | p0;
    slotB[t] = (i1 << 13) | p1;
    wAo[t] = w0;
    wBo[t] = w1;
}

// ---------------------------------------------------------------- combine
// Y[t] = wA[t]*scratch[gA] + wB[t]*scratch[gB]; scratch is bf16 (R13).
__global__ __launch_bounds__(256) void moe_combine_kernel(
        const unsigned short* __restrict__ scratch, const int* __restrict__ base,
        const int* __restrict__ slotA, const int* __restrict__ slotB,
        const float* __restrict__ wA, const float* __restrict__ wB,
        float* __restrict__ Y) {
    const int t = blockIdx.x;
    const int c = threadIdx.x * 8;
    const int sa = slotA[t];
    const int sb = slotB[t];
    const long gA = base[sa >> 13] + (sa & 8191);
    const long gB = base[sb >> 13] + (sb & 8191);
    const float wa = wA[t], wb = wB[t];
    s16x8_t a = __builtin_nontemporal_load((const s16x8_t*)(scratch + gA * DIM_OUT + c));
    s16x8_t b = __builtin_nontemporal_load((const s16x8_t*)(scratch + gB * DIM_OUT + c));
    f32x4_t y0, y1;
#pragma unroll
    for (int j = 0; j < 4; ++j) {
        y0[j] = wa * bf2f((unsigned short)a[j])     + wb * bf2f((unsigned short)b[j]);
        y1[j] = wa * bf2f((unsigned short)a[j + 4]) + wb * bf2f((unsigned short)b[j + 4]);
    }
    f32x4_t* y = (f32x4_t*)(Y + (long)t * DIM_OUT + c);
    y[0] = y0;
    y[1] = y1;
}

// ---------------------------------------------------------------- bf16 grouped GEMM
// R14: expert-per-XCD mapping (WIN: FETCH 307->119 MB, 175->158 us; kept).
// R13: bf16 scratch (WIN; kept). R11: tail path (neutral; kept).
// R15 delta: m201-style 4-phase fine interleave per K-tile (T3). The R8
// 2-phase loop had a ~1000-cyc serial fragment-read drain per tile with no
// MFMA to hide it (prev tile's MFMAs finish before the tile barrier), in-block
// efficiency 45% of MFMA floor. Now each tile = 4 phases, each
// {ds_read subtile (12/4/8/0) || 2 gloads -> barrier -> lgkmcnt(0) ->
//  16 MFMA -> barrier}, fragment reuse across phases (bfr live whole tile,
// af03 P1-P2, af47 P3-P4). vmcnt(6) once per tile at P4 end: queue there =
// [prev.P3 B 2, prev.P4 A 4, P1 Bnext 2, P3 B 2, P4 A 4]=14, drain-8 =
// exactly next buffer's loads. WAR safety: A-stage (P4) after af-reads
// drained (P1/P3 lgkm0 + barrier); B(CC,0)-stage (P3) after bfr reads
// drained (P2 lgkm0 + barrier). Same math, same staging map, same swizzle.
__global__ __launch_bounds__(512, 2) void moe_gemm_bf16(
        const unsigned short* __restrict__ Xb, const unsigned short* __restrict__ Wb,
        const float* __restrict__ bias,
        const int* __restrict__ counts, const int* __restrict__ lists,
        const float* __restrict__ lw, const int* __restrict__ base,
        unsigned short* __restrict__ scratch, float* __restrict__ Y) {
    // flat linear id (x fastest) -> (expert = XCD, m-chunk, col)
    const int L = blockIdx.x + (DIM_OUT / BN) * (blockIdx.y + (N_TOK / BM) * blockIdx.z);
    const int e = L & 7;                 // expert pinned to XCD (id % 8)
    const int idx = L >> 3;              // 0..255 within expert
    const int M = counts[e];
    const int m0 = (idx >> 3) * BM;      // m-chunk 0..31, m-major
    if (m0 >= M) return;
    int vr = M - m0; if (vr > BM) vr = BM;   // valid rows in this chunk
    const int col0 = (idx & 7) * BN;     // 8 cols of same m-chunk consecutive

    __shared__ unsigned short As[2][BM * BK];   // 2 x 32 KiB
    __shared__ unsigned short Bs[2][BN * BK];   // 2 x 32 KiB  (total 128 KiB)

    const int tid = threadIdx.x;
    const int lane = tid & 63;
    const int wid = tid >> 6;              // 0..7
    const int wn = (wid & 3) * 64;         // wave col offset: 0/64/128/192

    const int* mylist = lists + e * N_TOK + m0;
    const float* lwp = lw + e * N_TOK + m0;

    // staging map: thread t covers row (t>>3)+64i, 16 B at pre-swizzled col;
    // linear LDS dest byte = i*8192 + tid*16.
    const int srow = tid >> 3;                        // 0..63
    const int scol = ((tid & 7) ^ (srow & 7)) * 8;    // inverse-swizzled col

    const unsigned short* bptr = Wb + ((size_t)e * DIM_OUT + col0 + srow) * DIM_IN + scol;

    const int ldsbase = wid * 512;  // elements

    const int rl = lane & 15;
    const int hi = lane >> 4;
    const char* AsC = (const char*)As;
    const char* BsC = (const char*)Bs;

#define STAGE_B_H(buf, h, koff)                                                 \
    do {                                                                        \
        _Pragma("unroll")                                                       \
        for (int i = 2 * (h); i < 2 * (h) + 2; ++i)                             \
            gload_lds16(bptr + (size_t)(i * 64) * DIM_IN + (koff),              \
                        &Bs[buf][i * 4096 + ldsbase]);                          \
    } while (0)

    if (vr > 128) {
        // ======================= FULL PATH (R15 4-phase) =======================
        const int wm = (wid >> 2) * 128;       // wave row offset: 0 / 128

        const unsigned short* aptr[4];
#pragma unroll
        for (int i = 0; i < 4; ++i) {
            int r = srow + 64 * i;
            int tok = (m0 + r < M) ? mylist[r] : mylist[0];
            aptr[i] = Xb + (size_t)tok * DIM_IN + scol;
        }

        // hoisted lane-base byte offsets: full read addr = base + vX[kk] + IMM,
        // IMM = c*32768 + mblk*2048 (compile-time after unroll)
        unsigned vA[2], vB[2];
#pragma unroll
        for (int kk = 0; kk < 2; ++kk) {
            unsigned x = (unsigned)(((kk << 6) | (hi << 4)) ^ ((rl & 7) << 4));
            vA[kk] = (unsigned)((wm + rl) * 128) + x;
            vB[kk] = (unsigned)((wn + rl) * 128) + x;
        }

        f32x4_t acc[8][4];
#pragma unroll
        for (int m = 0; m < 8; ++m)
#pragma unroll
            for (int n = 0; n < 4; ++n)
                acc[m][n] = (f32x4_t)(0.0f);

#define STAGE_A_H(buf, h, koff)                                                 \
    do {                                                                        \
        _Pragma("unroll")                                                       \
        for (int i = 2 * (h); i < 2 * (h) + 2; ++i)                             \
            gload_lds16(aptr[i] + (koff), &As[buf][i * 4096 + ldsbase]);        \
    } while (0)

        // prologue: kt0 fully (8 loads), kt1 S0-S2 (6 loads) -> 14 outstanding;
        // then drain kt0's 8 so tile0's P1 ds_reads are safe.
        STAGE_A_H(0, 0, 0);  STAGE_A_H(0, 1, 0);  STAGE_B_H(0, 0, 0);  STAGE_B_H(0, 1, 0);
        STAGE_A_H(1, 0, BK); STAGE_A_H(1, 1, BK); STAGE_B_H(1, 0, BK);
        asm volatile("s_waitcnt vmcnt(6)" ::: "memory");
        __builtin_amdgcn_s_barrier();
        asm volatile("" ::: "memory");

        // one K-tile = 4 phases; CC is a literal 0/1
#define DO_TILE(CC, KOFN, KOF2)                                                 \
    {                                                                           \
        bf16x8_t bfr[4][2], af03[4][2], af47[4][2];                             \
        /* ---- P1: read bfr01(4) + af03(8); stage B(next,1); MFMA m0-3 x n0-1 */ \
        _Pragma("unroll")                                                       \
        for (int n = 0; n < 2; ++n)                                             \
            _Pragma("unroll")                                                   \
            for (int kk = 0; kk < 2; ++kk)                                      \
                bfr[n][kk] = *(const bf16x8_t*)(BsC + vB[kk] + ((CC) * 32768 + n * 2048)); \
        _Pragma("unroll")                                                       \
        for (int m = 0; m < 4; ++m)                                             \
            _Pragma("unroll")                                                   \
            for (int kk = 0; kk < 2; ++kk)                                      \
                af03[m][kk] = *(const bf16x8_t*)(AsC + vA[kk] + ((CC) * 32768 + m * 2048)); \
        STAGE_B_H(1 - (CC), 1, (KOFN));                                         \
        __builtin_amdgcn_s_barrier();                                           \
        asm volatile("" ::: "memory");                                          \
        asm volatile("s_waitcnt lgkmcnt(0)" ::: "memory");                      \
        __builtin_amdgcn_sched_barrier(0);                                      \
        __builtin_amdgcn_s_setprio(1);                                          \
        _Pragma("unroll")                                                       \
        for (int m = 0; m < 4; ++m)                                             \
            _Pragma("unroll")                                                   \
            for (int n = 0; n < 2; ++n)                                         \
                _Pragma("unroll")                                               \
                for (int kk = 0; kk < 2; ++kk)                                  \
                    acc[m][n] = __builtin_amdgcn_mfma_f32_16x16x32_bf16(af03[m][kk], bfr[n][kk], acc[m][n], 0, 0, 0); \
        __builtin_amdgcn_s_setprio(0);                                          \
        __builtin_amdgcn_s_barrier();                                           \
        asm volatile("" ::: "memory");                                          \
        /* ---- P2: read bfr23(4); MFMA m0-3 x n2-3 */                          \
        _Pragma("unroll")                                                       \
        for (int n = 2; n < 4; ++n)                                             \
            _Pragma("unroll")                                                   \
            for (int kk = 0; kk < 2; ++kk)                                      \
                bfr[n][kk] = *(const bf16x8_t*)(BsC + vB[kk] + ((CC) * 32768 + n * 2048)); \
        __builtin_amdgcn_s_barrier();                                           \
        asm volatile("" ::: "memory");                                          \
        asm volatile("s_waitcnt lgkmcnt(0)" ::: "memory");                      \
        __builtin_amdgcn_sched_barrier(0);                                      \
        __builtin_amdgcn_s_setprio(1);                                          \
        _Pragma("unroll")                                                       \
        for (int m = 0; m < 4; ++m)                                             \
            _Pragma("unroll")                                                   \
            for (int n = 2; n < 4; ++n)                                         \
                _Pragma("unroll")                                               \
                for (int kk = 0; kk < 2; ++kk)                                  \
                    acc[m][n] = __builtin_amdgcn_mfma_f32_16x16x32_bf16(af03[m][kk], bfr[n][kk], acc[m][n], 0, 0, 0); \
        __builtin_amdgcn_s_setprio(0);                                          \
        __builtin_amdgcn_s_barrier();                                           \
        asm volatile("" ::: "memory");                                          \
        /* ---- P3: read af47(8); stage B(cur,0)@KOF2; MFMA m4-7 x n0-1 */      \
        _Pragma("unroll")                                                       \
        for (int m = 0; m < 4; ++m)                                             \
            _Pragma("unroll")                                                   \
            for (int kk = 0; kk < 2; ++kk)                                      \
                af47[m][kk] = *(const bf16x8_t*)(AsC + vA[kk] + ((CC) * 32768 + (m + 4) * 2048)); \
        STAGE_B_H((CC), 0, (KOF2));                                             \
        __builtin_amdgcn_s_barrier();                                           \
        asm volatile("" ::: "memory");                                          \
        asm volatile("s_waitcnt lgkmcnt(0)" ::: "memory");                      \
        __builtin_amdgcn_sched_barrier(0);                                      \
        __builtin_amdgcn_s_setprio(1);                                          \
        _Pragma("unroll")                                                       \
        for (int m = 0; m < 4; ++m)                                             \
            _Pragma("unroll")                                                   \
            for (int n = 0; n < 2; ++n)                                         \
                _Pragma("unroll")                                               \
                for (int kk = 0; kk < 2; ++kk)                                  \
                    acc[m + 4][n] = __builtin_amdgcn_mfma_f32_16x16x32_bf16(af47[m][kk], bfr[n][kk], acc[m + 4][n], 0, 0, 0); \
        __builtin_amdgcn_s_setprio(0);                                          \
        __builtin_amdgcn_s_barrier();                                           \
        asm volatile("" ::: "memory");                                          \
        /* ---- P4: stage A(cur,0/1)@KOF2; MFMA m4-7 x n2-3; vmcnt(6) */        \
        STAGE_A_H((CC), 0, (KOF2));                                             \
        STAGE_A_H((CC), 1, (KOF2));                                             \
        __builtin_amdgcn_s_setprio(1);                                          \
        _Pragma("unroll")                                                       \
        for (int m = 0; m < 4; ++m)                                             \
            _Pragma("unroll")                                                   \
            for (int n = 2; n < 4; ++n)                                         \
                _Pragma("unroll")                                               \
                for (int kk = 0; kk < 2; ++kk)                                  \
                    acc[m + 4][n] = __builtin_amdgcn_mfma_f32_16x16x32_bf16(af47[m][kk], bfr[n][kk], acc[m + 4][n], 0, 0, 0); \
        __builtin_amdgcn_s_setprio(0);                                          \
        asm volatile("s_waitcnt vmcnt(6)" ::: "memory");                        \
        __builtin_amdgcn_s_barrier();                                           \
        asm volatile("" ::: "memory");                                          \
    }

        for (int kt = 0; kt < NKT; kt += 2) {
            const int kofn0 = (kt + 1) * BK;                                   // kt+1 <= 31
            const int kof20 = ((kt + 2 < NKT) ? (kt + 2) : (NKT - 1)) * BK;
            const int kofn1 = kof20;
            const int kof21 = ((kt + 3 < NKT) ? (kt + 3) : (NKT - 1)) * BK;
            DO_TILE(0, kofn0, kof20)
            DO_TILE(1, kofn1, kof21)
        }
        asm volatile("s_waitcnt vmcnt(0)" ::: "memory");   // drain phantom tail stages

        const int cl = lane & 15;
        const int rq = (lane >> 4) << 2;
        float biasv[4];
#pragma unroll
        for (int n = 0; n < 4; ++n) biasv[n] = bias[e * DIM_OUT + col0 + wn + n * 16 + cl];

        if (scratch) {
            const int segbase = base[e] + m0;
#pragma unroll
            for (int m = 0; m < 8; ++m) {
#pragma unroll
                for (int j = 0; j < 4; ++j) {
                    int row = wm + (m << 4) + rq + j;
                    if (m0 + row < M) {
                        short* out = (short*)(scratch + (size_t)(segbase + row) * DIM_OUT + col0 + wn);
#pragma unroll
                        for (int n = 0; n < 4; ++n)
                            __builtin_nontemporal_store(f2bf(acc[m][n][j] + biasv[n]), out + n * 16 + cl);
                    }
                }
            }
        } else {
#pragma unroll
            for (int m = 0; m < 8; ++m) {
#pragma unroll
                for (int j = 0; j < 4; ++j) {
                    int row = wm + (m << 4) + rq + j;
                    if (m0 + row < M) {
                        int tok = mylist[row];
                        float wgt = lwp[row];
                        float* yrow = Y + (size_t)tok * DIM_OUT + col0 + wn;
#pragma unroll
                        for (int n = 0; n < 4; ++n)
                            atomicAdd(yrow + n * 16 + cl, wgt * (acc[m][n][j] + biasv[n]));
                    }
                }
            }
        }
    } else {
        // ======================= TAIL PATH (vr <= 128, MF=4) =======================
        const int wm = (wid >> 2) * 64;        // 0 / 64

        const unsigned short* aptrT[2];
#pragma unroll
        for (int i = 0; i < 2; ++i) {
            int r = srow + 64 * i;
            int tok = (m0 + r < M) ? mylist[r] : mylist[0];
            aptrT[i] = Xb + (size_t)tok * DIM_IN + scol;
        }

        unsigned vA[2], vB[2];
#pragma unroll
        for (int kk = 0; kk < 2; ++kk) {
            unsigned x = (unsigned)(((kk << 6) | (hi << 4)) ^ ((rl & 7) << 4));
            vA[kk] = (unsigned)((wm + rl) * 128) + x;
            vB[kk] = (unsigned)((wn + rl) * 128) + x;
        }

        f32x4_t acc[4][4];
#pragma unroll
        for (int m = 0; m < 4; ++m)
#pragma unroll
            for (int n = 0; n < 4; ++n)
                acc[m][n] = (f32x4_t)(0.0f);

#define STAGE_A_T(buf, koff)                                                    \
    do {                                                                        \
        _Pragma("unroll")                                                       \
        for (int i = 0; i < 2; ++i)                                             \
            gload_lds16(aptrT[i] + (koff), &As[buf][i * 4096 + ldsbase]);       \
    } while (0)

        // prologue: kt0 fully (6 loads), kt1 A + B-half0 (4) -> 10 outstanding
        STAGE_A_T(0, 0);  STAGE_B_H(0, 0, 0);  STAGE_B_H(0, 1, 0);
        STAGE_A_T(1, BK); STAGE_B_H(1, 0, BK);

#define DO_TILE_T(CC, KOFN, KOF2)                                               \
    {                                                                           \
        asm volatile("s_waitcnt vmcnt(4)" ::: "memory");                        \
        __builtin_amdgcn_s_barrier();                                           \
        asm volatile("" ::: "memory");                                          \
        STAGE_B_H(1 - (CC), 1, (KOFN));                                         \
        bf16x8_t bfr[4][2], af[4][2];                                           \
        _Pragma("unroll")                                                       \
        for (int n = 0; n < 4; ++n)                                             \
            _Pragma("unroll")                                                   \
            for (int kk = 0; kk < 2; ++kk)                                      \
                bfr[n][kk] = *(const bf16x8_t*)(BsC + vB[kk] + ((CC) * 32768 + n * 2048)); \
        _Pragma("unroll")                                                       \
        for (int m = 0; m < 4; ++m)                                             \
            _Pragma("unroll")                                                   \
            for (int kk = 0; kk < 2; ++kk)                                      \
                af[m][kk] = *(const bf16x8_t*)(AsC + vA[kk] + ((CC) * 32768 + m * 2048)); \
        __builtin_amdgcn_s_setprio(1);                                          \
        _Pragma("unroll")                                                       \
        for (int m = 0; m < 2; ++m)                                             \
            _Pragma("unroll")                                                   \
            for (int n = 0; n < 4; ++n)                                         \
                _Pragma("unroll")                                               \
                for (int kk = 0; kk < 2; ++kk)                                  \
                    acc[m][n] = __builtin_amdgcn_mfma_f32_16x16x32_bf16(af[m][kk], bfr[n][kk], acc[m][n], 0, 0, 0); \
        __builtin_amdgcn_s_setprio(0);                                          \
        asm volatile("s_waitcnt lgkmcnt(0)" ::: "memory");                      \
        __builtin_amdgcn_sched_barrier(0);                                      \
        __builtin_amdgcn_s_barrier();                                           \
        asm volatile("" ::: "memory");                                          \
        STAGE_A_T((CC), (KOF2));                                                \
        __builtin_amdgcn_s_setprio(1);                                          \
        _Pragma("unroll")                                                       \
        for (int m = 2; m < 4; ++m)                                             \
            _Pragma("unroll")                                                   \
            for (int n = 0; n < 4; ++n)                                         \
                _Pragma("unroll")                                               \
                for (int kk = 0; kk < 2; ++kk)                                  \
                    acc[m][n] = __builtin_amdgcn_mfma_f32_16x16x32_bf16(af[m][kk], bfr[n][kk], acc[m][n], 0, 0, 0); \
        __builtin_amdgcn_s_setprio(0);                                          \
        STAGE_B_H((CC), 0, (KOF2));                                             \
    }

        for (int kt = 0; kt < NKT; kt += 2) {
            const int kofn0 = (kt + 1) * BK;
            const int kof20 = ((kt + 2 < NKT) ? (kt + 2) : (NKT - 1)) * BK;
            const int kofn1 = kof20;
            const int kof21 = ((kt + 3 < NKT) ? (kt + 3) : (NKT - 1)) * BK;
            DO_TILE_T(0, kofn0, kof20)
            DO_TILE_T(1, kofn1, kof21)
        }
        asm volatile("s_waitcnt vmcnt(0)" ::: "memory");   // drain phantom tail stages

        const int cl = lane & 15;
        const int rq = (lane >> 4) << 2;
        float biasv[4];
#pragma unroll
        for (int n = 0; n < 4; ++n) biasv[n] = bias[e * DIM_OUT + col0 + wn + n * 16 + cl];

        if (scratch) {
            const int segbase = base[e] + m0;
#pragma unroll
            for (int m = 0; m < 4; ++m) {
#pragma unroll
                for (int j = 0; j < 4; ++j) {
                    int row = wm + (m << 4) + rq + j;
                    if (m0 + row < M) {
                        short* out = (short*)(scratch + (size_t)(segbase + row) * DIM_OUT + col0 + wn);
#pragma unroll
                        for (int n = 0; n < 4; ++n)
                            __builtin_nontemporal_store(f2bf(acc[m][n][j] + biasv[n]), out + n * 16 + cl);
                    }
                }
            }
        } else {
#pragma unroll
            for (int m = 0; m < 4; ++m) {
#pragma unroll
                for (int j = 0; j < 4; ++j) {
                    int row = wm + (m << 4) + rq + j;
                    if (m0 + row < M) {
                        int tok = mylist[row];
                        float wgt = lwp[row];
                        float* yrow = Y + (size_t)tok * DIM_OUT + col0 + wn;
#pragma unroll
                        for (int n = 0; n < 4; ++n)
                            atomicAdd(yrow + n * 16 + cl, wgt * (acc[m][n][j] + biasv[n]));
                    }
                }
            }
        }
    }
#undef DO_TILE
#undef DO_TILE_T
#undef STAGE_A_H
#undef STAGE_A_T
#undef STAGE_B_H
}

// ---------------------------------------------------------------- f32 fallback GEMM (if ws too small)
__global__ __launch_bounds__(256, 2) void moe_gemm_f32(
        const float* __restrict__ X, const float* __restrict__ W,
        const float* __restrict__ bias,
        const int* __restrict__ counts, const int* __restrict__ lists,
        const float* __restrict__ lw, float* __restrict__ Y) {
    const int e = blockIdx.z;
    const int M = counts[e];
    const int m0 = blockIdx.y * 128;
    if (m0 >= M) return;
    const int col0 = blockIdx.x * 128;

    __shared__ short As[128 * 64];
    __shared__ short Bs[128 * 64];
    char* Ab = (char*)As;
    char* Bb = (char*)Bs;

    const int tid = threadIdx.x;
    const int lane = tid & 63;
    const int wid = tid >> 6;
    const int wm = (wid >> 1) * 64;
    const int wn = (wid & 1) * 64;

    const int* mylist = lists + e * N_TOK + m0;
    const float* lwp = lw + e * N_TOK + m0;

    const int srow = tid >> 4;
    const int scol = (tid & 15) << 2;
    const int swzW = (srow & 7) << 4;

    const float* xptr[8];
#pragma unroll
    for (int p = 0; p < 8; ++p) {
        int r = p * 16 + srow;
        int tok = (m0 + r < M) ? mylist[r] : mylist[0];
        xptr[p] = X + (size_t)tok * DIM_IN + scol;
    }
    const float* wptr = W + ((size_t)e * DIM_OUT + col0 + srow) * DIM_IN + scol;

    f32x4_t acc[4][4];
#pragma unroll
    for (int m = 0; m < 4; ++m)
#pragma unroll
        for (int n = 0; n < 4; ++n)
            acc[m][n] = (f32x4_t)(0.0f);

    for (int k0 = 0; k0 < DIM_IN; k0 += 64) {
#pragma unroll
        for (int p = 0; p < 8; ++p) {
            int r = p * 16 + srow;
            unsigned byteoff = (unsigned)(r * 128 + scol * 2) ^ swzW;
            float4 va = *(const float4*)(xptr[p] + k0);
            s16x4_t ha; ha[0] = f2bf(va.x); ha[1] = f2bf(va.y); ha[2] = f2bf(va.z); ha[3] = f2bf(va.w);
            *(s16x4_t*)(Ab + byteoff) = ha;
            float4 vb = *(const float4*)(wptr + (size_t)p * 16 * DIM_IN + k0);
            s16x4_t hb; hb[0] = f2bf(vb.x); hb[1] = f2bf(vb.y); hb[2] = f2bf(vb.z); hb[3] = f2bf(vb.w);
            *(s16x4_t*)(Bb + byteoff) = hb;
        }
        __syncthreads();

#pragma unroll
        for (int kk = 0; kk < 2; ++kk) {
            const int kb = (kk << 6) + ((lane >> 4) << 4);
            bf16x8_t af[4], bfr[4];
#pragma unroll
            for (int m = 0; m < 4; ++m) {
                int r = wm + (m << 4) + (lane & 15);
                unsigned byteoff = (unsigned)(r * 128 + kb) ^ ((unsigned)(r & 7) << 4);
                af[m] = *(const bf16x8_t*)(Ab + byteoff);
            }
#pragma unroll
            for (int n = 0; n < 4; ++n) {
                int r = wn + (n << 4) + (lane & 15);
                unsigned byteoff = (unsigned)(r * 128 + kb) ^ ((unsigned)(r & 7) << 4);
                bfr[n] = *(const bf16x8_t*)(Bb + byteoff);
            }
#pragma unroll
            for (int m = 0; m < 4; ++m)
#pragma unroll
                for (int n = 0; n < 4; ++n)
                    acc[m][n] = __builtin_amdgcn_mfma_f32_16x16x32_bf16(af[m], bfr[n], acc[m][n], 0, 0, 0);
        }
        __syncthreads();
    }

    const int cl = lane & 15;
    const int rq = (lane >> 4) << 2;
    float biasv[4];
#pragma unroll
    for (int n = 0; n < 4; ++n) biasv[n] = bias[e * DIM_OUT + col0 + wn + n * 16 + cl];
#pragma unroll
    for (int m = 0; m < 4; ++m) {
#pragma unroll
        for (int j = 0; j < 4; ++j) {
            int row = wm + (m << 4) + rq + j;
            if (m0 + row < M) {
                int tok = mylist[row];
                float wgt = lwp[row];
                float* yrow = Y + (size_t)tok * DIM_OUT + col0 + wn;
#pragma unroll
                for (int n = 0; n < 4; ++n)
                    atomicAdd(yrow + n * 16 + cl, wgt * (acc[m][n][j] + biasv[n]));
            }
        }
    }
}

extern "C" void kernel_launch(void* const* d_in, const int* in_sizes, int n_in,
                              void* d_out, int out_size, void* d_ws, size_t ws_size,
                              hipStream_t stream) {
    const float* X = (const float*)d_in[0];
    const float* G = (const float*)d_in[1];
    const float* W = (const float*)d_in[2];
    const float* b = (const float*)d_in[3];
    float* Y = (float*)d_out;

    char* ws = (char*)d_ws;
    int*   counts = (int*)ws;                       // 32 B
    int*   base   = (int*)(ws + 64);                // 36 B
    int*   slotA  = (int*)(ws + 256);               // 32 KiB
    int*   slotB  = (int*)(ws + 256 + 32768);       // 32 KiB
    float* wA     = (float*)(ws + 256 + 65536);     // 32 KiB
    float* wB     = (float*)(ws + 256 + 98304);     // 32 KiB
    int*   lists  = (int*)(ws + 256 + 131072);      // 256 KiB
    float* lw     = (float*)(ws + 256 + 131072 + 262144);  // 256 KiB
    size_t o_Xb   = 256 + 131072 + 2 * 262144;
    unsigned short* Xb = (unsigned short*)(ws + o_Xb);
    size_t o_Wb   = o_Xb + (size_t)NX_ELEMS * 2;
    unsigned short* Wb = (unsigned short*)(ws + o_Wb);
    size_t o_scr  = o_Wb + (size_t)NW_ELEMS * 2;
    unsigned short* scratch = (unsigned short*)(ws + o_scr);
    const size_t ws_need_mid  = o_scr;                                    // ~96.6 MiB
    const size_t ws_need_full = o_scr + (size_t)2 * N_TOK * DIM_OUT * 2;  // ~160.6 MiB (bf16 scratch)

    const bool use_scratch = (ws_size >= ws_need_full);
    const bool use_bf16    = (ws_size >= ws_need_mid);

    if (use_scratch) {
        moe_zero_kernel<<<1, 256, 0, stream>>>((float4*)Y, 0, counts);
    } else {
        moe_zero_kernel<<<2048, 256, 0, stream>>>((float4*)Y, out_size / 4, counts);
    }
    moe_gate_kernel<<<(N_TOK + 255) / 256, 256, 0, stream>>>(G, counts, lists, lw,
                                                             slotA, slotB, wA, wB);

    if (use_bf16) {
        moe_cvt_kernel<<<2048, 256, 0, stream>>>(X, W, Xb, Wb, counts, base);
        dim3 grid(DIM_OUT / BN, N_TOK / BM, N_EXP);
        moe_gemm_bf16<<<grid, 512, 0, stream>>>(Xb, Wb, b, counts, lists, lw, base,
                                                use_scratch ? scratch : nullptr, Y);
        if (use_scratch) {
            moe_combine_kernel<<<N_TOK, 256, 0, stream>>>(scratch, base, slotA, slotB,
                                                          wA, wB, Y);
        }
    } else {
        dim3 grid(DIM_OUT / 128, N_TOK / 128, N_EXP);
        moe_gemm_f32<<<grid, 256, 0, stream>>>(X, W, b, counts, lists, lw, Y);
    }
}

// Round 7
// 294.578 us; speedup vs baseline: 1.0245x; 1.0245x over previous
//
#include <hip/hip_runtime.h>
#include <hip/hip_bf16.h>

#define N_TOK 8192
#define N_EXP 8
#define DIM_IN 2048
#define DIM_OUT 2048

#define BM 256
#define BN 256
#define BK 64
#define NKT (DIM_IN / BK)   // 32 K-tiles

#define NX_ELEMS (N_TOK * DIM_IN)              // 16,777,216
#define NW_ELEMS (N_EXP * DIM_OUT * DIM_IN)    // 33,554,432

typedef __attribute__((ext_vector_type(8))) short bf16x8_t;
typedef __attribute__((ext_vector_type(8))) short s16x8_t;
typedef __attribute__((ext_vector_type(4))) short s16x4_t;
typedef __attribute__((ext_vector_type(4))) float f32x4_t;

__device__ __forceinline__ short f2bf(float f) {
    union { __hip_bfloat16 h; short s; } u;
    u.h = __float2bfloat16(f);
    return u.s;
}

__device__ __forceinline__ float bf2f(unsigned short s) {
    union { float f; unsigned u; } v;
    v.u = ((unsigned)s) << 16;
    return v.f;
}

__device__ __forceinline__ void gload_lds16(const void* g, void* l) {
    __builtin_amdgcn_global_load_lds(
        (const __attribute__((address_space(1))) void*)g,
        (__attribute__((address_space(3))) void*)l, 16, 0, 0);
}

// ---------------------------------------------------------------- zero kernel (non-scratch fallback only)
__global__ void moe_zero_kernel(float4* __restrict__ y, int n4, int* __restrict__ counts) {
    int i = blockIdx.x * blockDim.x + threadIdx.x;
    if (i < N_EXP) counts[i] = 0;
    float4 z; z.x = 0.f; z.y = 0.f; z.z = 0.f; z.w = 0.f;
    for (; i < n4; i += gridDim.x * blockDim.x) y[i] = z;
}

// ---------------------------------------------------------------- fused gate + f32->bf16 convert (R16)
// Gating for all 8192 tokens runs in the first 32 blocks' first pass; every
// block then grid-strides the X/W conversion. One launch instead of two; the
// base prefix-sum moved inline into GEMM/combine (8 scalar count reads).
__global__ void moe_gate_cvt_kernel(const float* __restrict__ G,
                                    const float* __restrict__ X, const float* __restrict__ W,
                                    int* __restrict__ counts,
                                    int* __restrict__ lists, float* __restrict__ lw,
                                    int* __restrict__ slotA, int* __restrict__ slotB,
                                    float* __restrict__ wAo, float* __restrict__ wBo,
                                    unsigned short* __restrict__ Xb, unsigned short* __restrict__ Wb) {
    const int t = blockIdx.x * blockDim.x + threadIdx.x;
    if (t < N_TOK) {
        float g[N_EXP];
#pragma unroll
        for (int e = 0; e < N_EXP; ++e) g[e] = G[t * N_EXP + e];
        int i0 = 0; float b0 = g[0];
#pragma unroll
        for (int e = 1; e < N_EXP; ++e) if (g[e] > b0) { b0 = g[e]; i0 = e; }
        int i1 = -1; float b1 = -INFINITY;
#pragma unroll
        for (int e = 0; e < N_EXP; ++e) if (e != i0 && g[e] > b1) { b1 = g[e]; i1 = e; }
        float e1 = expf(b1 - b0);
        float w0 = 1.0f / (1.0f + e1);
        float w1 = e1 * w0;
        int p0 = atomicAdd(&counts[i0], 1);
        lists[i0 * N_TOK + p0] = t;
        lw[i0 * N_TOK + p0] = w0;
        int p1 = atomicAdd(&counts[i1], 1);
        lists[i1 * N_TOK + p1] = t;
        lw[i1 * N_TOK + p1] = w1;
        slotA[t] = (i0 << 13) | p0;
        slotB[t] = (i1 << 13) | p1;
        wAo[t] = w0;
        wBo[t] = w1;
    }
    const long long total8 = (long long)(NX_ELEMS + NW_ELEMS) / 8;
    for (long long i = blockIdx.x * blockDim.x + threadIdx.x; i < total8;
         i += (long long)gridDim.x * blockDim.x) {
        long long b8 = i * 8;
        const float* src;
        unsigned short* dst;
        if (b8 < NX_ELEMS) { src = X + b8; dst = Xb + b8; }
        else { src = W + (b8 - NX_ELEMS); dst = Wb + (b8 - NX_ELEMS); }
        // nontemporal: f32 inputs are never re-read; keep LLC for Xb/Wb/scratch.
        f32x4_t a = __builtin_nontemporal_load((const f32x4_t*)src);
        f32x4_t b = __builtin_nontemporal_load((const f32x4_t*)(src + 4));
        s16x8_t h;
        h[0] = f2bf(a[0]); h[1] = f2bf(a[1]); h[2] = f2bf(a[2]); h[3] = f2bf(a[3]);
        h[4] = f2bf(b[0]); h[5] = f2bf(b[1]); h[6] = f2bf(b[2]); h[7] = f2bf(b[3]);
        *(s16x8_t*)dst = h;
    }
}

// ---------------------------------------------------------------- gating (f32 fallback path only)
__global__ void moe_gate_kernel(const float* __restrict__ G,
                                int* __restrict__ counts,
                                int* __restrict__ lists,
                                float* __restrict__ lw,
                                int* __restrict__ slotA, int* __restrict__ slotB,
                                float* __restrict__ wAo, float* __restrict__ wBo) {
    int t = blockIdx.x * blockDim.x + threadIdx.x;
    if (t >= N_TOK) return;
    float g[N_EXP];
#pragma unroll
    for (int e = 0; e < N_EXP; ++e) g[e] = G[t * N_EXP + e];
    int i0 = 0; float b0 = g[0];
#pragma unroll
    for (int e = 1; e < N_EXP; ++e) if (g[e] > b0) { b0 = g[e]; i0 = e; }
    int i1 = -1; float b1 = -INFINITY;
#pragma unroll
    for (int e = 0; e < N_EXP; ++e) if (e != i0 && g[e] > b1) { b1 = g[e]; i1 = e; }
    float e1 = expf(b1 - b0);
    float w0 = 1.0f / (1.0f + e1);
    float w1 = e1 * w0;
    int p0 = atomicAdd(&counts[i0], 1);
    lists[i0 * N_TOK + p0] = t;
    lw[i0 * N_TOK + p0] = w0;
    int p1 = atomicAdd(&counts[i1], 1);
    lists[i1 * N_TOK + p1] = t;
    lw[i1 * N_TOK + p1] = w1;
    slotA[t] = (i0 << 13) | p0;
    slotB[t] = (i1 << 13) | p1;
    wAo[t] = w0;
    wBo[t] = w1;
}

// ---------------------------------------------------------------- combine
// Y[t] = wA[t]*scratch[gA] + wB[t]*scratch[gB]; scratch is bf16 (R13).
// R16: base prefix computed inline from counts (8 uniform loads).
__global__ __launch_bounds__(256) void moe_combine_kernel(
        const unsigned short* __restrict__ scratch, const int* __restrict__ counts,
        const int* __restrict__ slotA, const int* __restrict__ slotB,
        const float* __restrict__ wA, const float* __restrict__ wB,
        float* __restrict__ Y) {
    const int t = blockIdx.x;
    const int c = threadIdx.x * 8;
    const int sa = slotA[t];
    const int sb = slotB[t];
    const int eA = sa >> 13, eB = sb >> 13;
    int baseA = 0, baseB = 0;
#pragma unroll
    for (int i = 0; i < N_EXP; ++i) {
        int cv = counts[i];
        baseA += (i < eA) ? cv : 0;
        baseB += (i < eB) ? cv : 0;
    }
    const long gA = baseA + (sa & 8191);
    const long gB = baseB + (sb & 8191);
    const float wa = wA[t], wb = wB[t];
    s16x8_t a = __builtin_nontemporal_load((const s16x8_t*)(scratch + gA * DIM_OUT + c));
    s16x8_t b = __builtin_nontemporal_load((const s16x8_t*)(scratch + gB * DIM_OUT + c));
    f32x4_t y0, y1;
#pragma unroll
    for (int j = 0; j < 4; ++j) {
        y0[j] = wa * bf2f((unsigned short)a[j])     + wb * bf2f((unsigned short)b[j]);
        y1[j] = wa * bf2f((unsigned short)a[j + 4]) + wb * bf2f((unsigned short)b[j + 4]);
    }
    f32x4_t* y = (f32x4_t*)(Y + (long)t * DIM_OUT + c);
    y[0] = y0;
    y[1] = y1;
}

// ---------------------------------------------------------------- bf16 grouped GEMM
// R8 schedule (measured best, 158 us x3): 256x256, 8 waves (2Mx4N), BK=64,
// dbuf, write-behind-read-front, counted vmcnt(6), one vmcnt + 2 barriers/tile.
// R10: LDS addresses hoisted to lane-base VGPRs, offsets in ds_read imms.
// R11: tail path for vr<=128 (neutral; kept).
// R13: bf16 scratch (WIN; kept).
// R14: expert-per-XCD mapping (WIN: FETCH 307->119 MB; kept).
// R15 4-phase interleave REGRESSED (158->168, MfmaUtil down) -> reverted to R8.
// R16: base prefix-sum computed inline (epilogue-only, 8 scalar loads).
__global__ __launch_bounds__(512, 2) void moe_gemm_bf16(
        const unsigned short* __restrict__ Xb, const unsigned short* __restrict__ Wb,
        const float* __restrict__ bias,
        const int* __restrict__ counts, const int* __restrict__ lists,
        const float* __restrict__ lw,
        unsigned short* __restrict__ scratch, float* __restrict__ Y) {
    // flat linear id (x fastest) -> (expert = XCD, m-chunk, col)
    const int L = blockIdx.x + (DIM_OUT / BN) * (blockIdx.y + (N_TOK / BM) * blockIdx.z);
    const int e = L & 7;                 // expert pinned to XCD (id % 8)
    const int idx = L >> 3;              // 0..255 within expert
    const int M = counts[e];
    const int m0 = (idx >> 3) * BM;      // m-chunk 0..31, m-major
    if (m0 >= M) return;
    int vr = M - m0; if (vr > BM) vr = BM;   // valid rows in this chunk
    const int col0 = (idx & 7) * BN;     // 8 cols of same m-chunk consecutive

    __shared__ unsigned short As[2][BM * BK];   // 2 x 32 KiB
    __shared__ unsigned short Bs[2][BN * BK];   // 2 x 32 KiB  (total 128 KiB)

    const int tid = threadIdx.x;
    const int lane = tid & 63;
    const int wid = tid >> 6;              // 0..7
    const int wn = (wid & 3) * 64;         // wave col offset: 0/64/128/192

    const int* mylist = lists + e * N_TOK + m0;
    const float* lwp = lw + e * N_TOK + m0;

    // staging map: thread t covers row (t>>3)+64i, 16 B at pre-swizzled col;
    // linear LDS dest byte = i*8192 + tid*16.
    const int srow = tid >> 3;                        // 0..63
    const int scol = ((tid & 7) ^ (srow & 7)) * 8;    // inverse-swizzled col

    const unsigned short* bptr = Wb + ((size_t)e * DIM_OUT + col0 + srow) * DIM_IN + scol;

    const int ldsbase = wid * 512;  // elements

    const int rl = lane & 15;
    const int hi = lane >> 4;
    const char* AsC = (const char*)As;
    const char* BsC = (const char*)Bs;

#define STAGE_B_H(buf, h, koff)                                                 \
    do {                                                                        \
        _Pragma("unroll")                                                       \
        for (int i = 2 * (h); i < 2 * (h) + 2; ++i)                             \
            gload_lds16(bptr + (size_t)(i * 64) * DIM_IN + (koff),              \
                        &Bs[buf][i * 4096 + ldsbase]);                          \
    } while (0)

    if (vr > 128) {
        // ======================= FULL PATH (R8 schedule) =======================
        const int wm = (wid >> 2) * 128;       // wave row offset: 0 / 128

        const unsigned short* aptr[4];
#pragma unroll
        for (int i = 0; i < 4; ++i) {
            int r = srow + 64 * i;
            int tok = (m0 + r < M) ? mylist[r] : mylist[0];
            aptr[i] = Xb + (size_t)tok * DIM_IN + scol;
        }

        // hoisted lane-base byte offsets: full read addr = base + vX[kk] + IMM,
        // IMM = c*32768 + mblk*2048 (compile-time after unroll)
        unsigned vA[2], vB[2];
#pragma unroll
        for (int kk = 0; kk < 2; ++kk) {
            unsigned x = (unsigned)(((kk << 6) | (hi << 4)) ^ ((rl & 7) << 4));
            vA[kk] = (unsigned)((wm + rl) * 128) + x;
            vB[kk] = (unsigned)((wn + rl) * 128) + x;
        }

        f32x4_t acc[8][4];
#pragma unroll
        for (int m = 0; m < 8; ++m)
#pragma unroll
            for (int n = 0; n < 4; ++n)
                acc[m][n] = (f32x4_t)(0.0f);

#define STAGE_A_H(buf, h, koff)                                                 \
    do {                                                                        \
        _Pragma("unroll")                                                       \
        for (int i = 2 * (h); i < 2 * (h) + 2; ++i)                             \
            gload_lds16(aptr[i] + (koff), &As[buf][i * 4096 + ldsbase]);        \
    } while (0)

        // prologue: kt0 fully (8 loads), kt1 S0-S2 (6 loads) -> 14 outstanding
        STAGE_A_H(0, 0, 0);  STAGE_A_H(0, 1, 0);  STAGE_B_H(0, 0, 0);  STAGE_B_H(0, 1, 0);
        STAGE_A_H(1, 0, BK); STAGE_A_H(1, 1, BK); STAGE_B_H(1, 0, BK);

        // one tile of the R8 schedule; CC is a literal 0/1
#define DO_TILE(CC, KOFN, KOF2)                                                 \
    {                                                                           \
        asm volatile("s_waitcnt vmcnt(6)" ::: "memory");                        \
        __builtin_amdgcn_s_barrier();                                           \
        asm volatile("" ::: "memory");                                          \
        STAGE_B_H(1 - (CC), 1, (KOFN));                                         \
        bf16x8_t bfr[4][2], af0[4][2], af1[4][2];                               \
        _Pragma("unroll")                                                       \
        for (int n = 0; n < 4; ++n)                                             \
            _Pragma("unroll")                                                   \
            for (int kk = 0; kk < 2; ++kk)                                      \
                bfr[n][kk] = *(const bf16x8_t*)(BsC + vB[kk] + ((CC) * 32768 + n * 2048)); \
        _Pragma("unroll")                                                       \
        for (int m = 0; m < 4; ++m)                                             \
            _Pragma("unroll")                                                   \
            for (int kk = 0; kk < 2; ++kk)                                      \
                af0[m][kk] = *(const bf16x8_t*)(AsC + vA[kk] + ((CC) * 32768 + m * 2048)); \
        __builtin_amdgcn_s_setprio(1);                                          \
        _Pragma("unroll")                                                       \
        for (int m = 0; m < 2; ++m)                                             \
            _Pragma("unroll")                                                   \
            for (int n = 0; n < 4; ++n)                                         \
                _Pragma("unroll")                                               \
                for (int kk = 0; kk < 2; ++kk)                                  \
                    acc[m][n] = __builtin_amdgcn_mfma_f32_16x16x32_bf16(af0[m][kk], bfr[n][kk], acc[m][n], 0, 0, 0); \
        __builtin_amdgcn_s_setprio(0);                                          \
        _Pragma("unroll")                                                       \
        for (int m = 0; m < 4; ++m)                                             \
            _Pragma("unroll")                                                   \
            for (int kk = 0; kk < 2; ++kk)                                      \
                af1[m][kk] = *(const bf16x8_t*)(AsC + vA[kk] + ((CC) * 32768 + (m + 4) * 2048)); \
        __builtin_amdgcn_s_setprio(1);                                          \
        _Pragma("unroll")                                                       \
        for (int m = 2; m < 4; ++m)                                             \
            _Pragma("unroll")                                                   \
            for (int n = 0; n < 4; ++n)                                         \
                _Pragma("unroll")                                               \
                for (int kk = 0; kk < 2; ++kk)                                  \
                    acc[m][n] = __builtin_amdgcn_mfma_f32_16x16x32_bf16(af0[m][kk], bfr[n][kk], acc[m][n], 0, 0, 0); \
        __builtin_amdgcn_s_setprio(0);                                          \
        asm volatile("s_waitcnt lgkmcnt(0)" ::: "memory");                      \
        __builtin_amdgcn_sched_barrier(0);                                      \
        __builtin_amdgcn_s_barrier();                                           \
        asm volatile("" ::: "memory");                                          \
        STAGE_A_H((CC), 0, (KOF2));                                             \
        __builtin_amdgcn_s_setprio(1);                                          \
        _Pragma("unroll")                                                       \
        for (int m = 0; m < 2; ++m)                                             \
            _Pragma("unroll")                                                   \
            for (int n = 0; n < 4; ++n)                                         \
                _Pragma("unroll")                                               \
                for (int kk = 0; kk < 2; ++kk)                                  \
                    acc[m + 4][n] = __builtin_amdgcn_mfma_f32_16x16x32_bf16(af1[m][kk], bfr[n][kk], acc[m + 4][n], 0, 0, 0); \
        __builtin_amdgcn_s_setprio(0);                                          \
        STAGE_A_H((CC), 1, (KOF2));                                             \
        __builtin_amdgcn_s_setprio(1);                                          \
        _Pragma("unroll")                                                       \
        for (int n = 0; n < 4; ++n)                                             \
            _Pragma("unroll")                                                   \
            for (int kk = 0; kk < 2; ++kk)                                      \
                acc[6][n] = __builtin_amdgcn_mfma_f32_16x16x32_bf16(af1[2][kk], bfr[n][kk], acc[6][n], 0, 0, 0); \
        __builtin_amdgcn_s_setprio(0);                                          \
        STAGE_B_H((CC), 0, (KOF2));                                             \
        __builtin_amdgcn_s_setprio(1);                                          \
        _Pragma("unroll")                                                       \
        for (int n = 0; n < 4; ++n)                                             \
            _Pragma("unroll")                                                   \
            for (int kk = 0; kk < 2; ++kk)                                      \
                acc[7][n] = __builtin_amdgcn_mfma_f32_16x16x32_bf16(af1[3][kk], bfr[n][kk], acc[7][n], 0, 0, 0); \
        __builtin_amdgcn_s_setprio(0);                                          \
    }

        for (int kt = 0; kt < NKT; kt += 2) {
            const int kofn0 = (kt + 1) * BK;                                   // kt+1 <= 31
            const int kof20 = ((kt + 2 < NKT) ? (kt + 2) : (NKT - 1)) * BK;
            const int kofn1 = kof20;
            const int kof21 = ((kt + 3 < NKT) ? (kt + 3) : (NKT - 1)) * BK;
            DO_TILE(0, kofn0, kof20)
            DO_TILE(1, kofn1, kof21)
        }
        asm volatile("s_waitcnt vmcnt(0)" ::: "memory");   // drain phantom tail stages

        const int cl = lane & 15;
        const int rq = (lane >> 4) << 2;
        float biasv[4];
#pragma unroll
        for (int n = 0; n < 4; ++n) biasv[n] = bias[e * DIM_OUT + col0 + wn + n * 16 + cl];

        if (scratch) {
            int segbase = m0;
            for (int i = 0; i < e; ++i) segbase += counts[i];
#pragma unroll
            for (int m = 0; m < 8; ++m) {
#pragma unroll
                for (int j = 0; j < 4; ++j) {
                    int row = wm + (m << 4) + rq + j;
                    if (m0 + row < M) {
                        short* out = (short*)(scratch + (size_t)(segbase + row) * DIM_OUT + col0 + wn);
#pragma unroll
                        for (int n = 0; n < 4; ++n)
                            __builtin_nontemporal_store(f2bf(acc[m][n][j] + biasv[n]), out + n * 16 + cl);
                    }
                }
            }
        } else {
#pragma unroll
            for (int m = 0; m < 8; ++m) {
#pragma unroll
                for (int j = 0; j < 4; ++j) {
                    int row = wm + (m << 4) + rq + j;
                    if (m0 + row < M) {
                        int tok = mylist[row];
                        float wgt = lwp[row];
                        float* yrow = Y + (size_t)tok * DIM_OUT + col0 + wn;
#pragma unroll
                        for (int n = 0; n < 4; ++n)
                            atomicAdd(yrow + n * 16 + cl, wgt * (acc[m][n][j] + biasv[n]));
                    }
                }
            }
        }
    } else {
        // ======================= TAIL PATH (vr <= 128, MF=4) =======================
        const int wm = (wid >> 2) * 64;        // 0 / 64

        const unsigned short* aptrT[2];
#pragma unroll
        for (int i = 0; i < 2; ++i) {
            int r = srow + 64 * i;
            int tok = (m0 + r < M) ? mylist[r] : mylist[0];
            aptrT[i] = Xb + (size_t)tok * DIM_IN + scol;
        }

        unsigned vA[2], vB[2];
#pragma unroll
        for (int kk = 0; kk < 2; ++kk) {
            unsigned x = (unsigned)(((kk << 6) | (hi << 4)) ^ ((rl & 7) << 4));
            vA[kk] = (unsigned)((wm + rl) * 128) + x;
            vB[kk] = (unsigned)((wn + rl) * 128) + x;
        }

        f32x4_t acc[4][4];
#pragma unroll
        for (int m = 0; m < 4; ++m)
#pragma unroll
            for (int n = 0; n < 4; ++n)
                acc[m][n] = (f32x4_t)(0.0f);

#define STAGE_A_T(buf, koff)                                                    \
    do {                                                                        \
        _Pragma("unroll")                                                       \
        for (int i = 0; i < 2; ++i)                                             \
            gload_lds16(aptrT[i] + (koff), &As[buf][i * 4096 + ldsbase]);       \
    } while (0)

        // prologue: kt0 fully (6 loads), kt1 A + B-half0 (4) -> 10 outstanding
        STAGE_A_T(0, 0);  STAGE_B_H(0, 0, 0);  STAGE_B_H(0, 1, 0);
        STAGE_A_T(1, BK); STAGE_B_H(1, 0, BK);

#define DO_TILE_T(CC, KOFN, KOF2)                                               \
    {                                                                           \
        asm volatile("s_waitcnt vmcnt(4)" ::: "memory");                        \
        __builtin_amdgcn_s_barrier();                                           \
        asm volatile("" ::: "memory");                                          \
        STAGE_B_H(1 - (CC), 1, (KOFN));                                         \
        bf16x8_t bfr[4][2], af[4][2];                                           \
        _Pragma("unroll")                                                       \
        for (int n = 0; n < 4; ++n)                                             \
            _Pragma("unroll")                                                   \
            for (int kk = 0; kk < 2; ++kk)                                      \
                bfr[n][kk] = *(const bf16x8_t*)(BsC + vB[kk] + ((CC) * 32768 + n * 2048)); \
        _Pragma("unroll")                                                       \
        for (int m = 0; m < 4; ++m)                                             \
            _Pragma("unroll")                                                   \
            for (int kk = 0; kk < 2; ++kk)                                      \
                af[m][kk] = *(const bf16x8_t*)(AsC + vA[kk] + ((CC) * 32768 + m * 2048)); \
        __builtin_amdgcn_s_setprio(1);                                          \
        _Pragma("unroll")                                                       \
        for (int m = 0; m < 2; ++m)                                             \
            _Pragma("unroll")                                                   \
            for (int n = 0; n < 4; ++n)                                         \
                _Pragma("unroll")                                               \
                for (int kk = 0; kk < 2; ++kk)                                  \
                    acc[m][n] = __builtin_amdgcn_mfma_f32_16x16x32_bf16(af[m][kk], bfr[n][kk], acc[m][n], 0, 0, 0); \
        __builtin_amdgcn_s_setprio(0);                                          \
        asm volatile("s_waitcnt lgkmcnt(0)" ::: "memory");                      \
        __builtin_amdgcn_sched_barrier(0);                                      \
        __builtin_amdgcn_s_barrier();                                           \
        asm volatile("" ::: "memory");                                          \
        STAGE_A_T((CC), (KOF2));                                                \
        __builtin_amdgcn_s_setprio(1);                                          \
        _Pragma("unroll")                                                       \
        for (int m = 2; m < 4; ++m)                                             \
            _Pragma("unroll")                                                   \
            for (int n = 0; n < 4; ++n)                                         \
                _Pragma("unroll")                                               \
                for (int kk = 0; kk < 2; ++kk)                                  \
                    acc[m][n] = __builtin_amdgcn_mfma_f32_16x16x32_bf16(af[m][kk], bfr[n][kk], acc[m][n], 0, 0, 0); \
        __builtin_amdgcn_s_setprio(0);                                          \
        STAGE_B_H((CC), 0, (KOF2));                                             \
    }

        for (int kt = 0; kt < NKT; kt += 2) {
            const int kofn0 = (kt + 1) * BK;
            const int kof20 = ((kt + 2 < NKT) ? (kt + 2) : (NKT - 1)) * BK;
            const int kofn1 = kof20;
            const int kof21 = ((kt + 3 < NKT) ? (kt + 3) : (NKT - 1)) * BK;
            DO_TILE_T(0, kofn0, kof20)
            DO_TILE_T(1, kofn1, kof21)
        }
        asm volatile("s_waitcnt vmcnt(0)" ::: "memory");   // drain phantom tail stages

        const int cl = lane & 15;
        const int rq = (lane >> 4) << 2;
        float biasv[4];
#pragma unroll
        for (int n = 0; n < 4; ++n) biasv[n] = bias[e * DIM_OUT + col0 + wn + n * 16 + cl];

        if (scratch) {
            int segbase = m0;
            for (int i = 0; i < e; ++i) segbase += counts[i];
#pragma unroll
            for (int m = 0; m < 4; ++m) {
#pragma unroll
                for (int j = 0; j < 4; ++j) {
                    int row = wm + (m << 4) + rq + j;
                    if (m0 + row < M) {
                        short* out = (short*)(scratch + (size_t)(segbase + row) * DIM_OUT + col0 + wn);
#pragma unroll
                        for (int n = 0; n < 4; ++n)
                            __builtin_nontemporal_store(f2bf(acc[m][n][j] + biasv[n]), out + n * 16 + cl);
                    }
                }
            }
        } else {
#pragma unroll
            for (int m = 0; m < 4; ++m) {
#pragma unroll
                for (int j = 0; j < 4; ++j) {
                    int row = wm + (m << 4) + rq + j;
                    if (m0 + row < M) {
                        int tok = mylist[row];
                        float wgt = lwp[row];
                        float* yrow = Y + (size_t)tok * DIM_OUT + col0 + wn;
#pragma unroll
                        for (int n = 0; n < 4; ++n)
                            atomicAdd(yrow + n * 16 + cl, wgt * (acc[m][n][j] + biasv[n]));
                    }
                }
            }
        }
    }
#undef DO_TILE
#undef DO_TILE_T
#undef STAGE_A_H
#undef STAGE_A_T
#undef STAGE_B_H
}

// ---------------------------------------------------------------- f32 fallback GEMM (if ws too small)
__global__ __launch_bounds__(256, 2) void moe_gemm_f32(
        const float* __restrict__ X, const float* __restrict__ W,
        const float* __restrict__ bias,
        const int* __restrict__ counts, const int* __restrict__ lists,
        const float* __restrict__ lw, float* __restrict__ Y) {
    const int e = blockIdx.z;
    const int M = counts[e];
    const int m0 = blockIdx.y * 128;
    if (m0 >= M) return;
    const int col0 = blockIdx.x * 128;

    __shared__ short As[128 * 64];
    __shared__ short Bs[128 * 64];
    char* Ab = (char*)As;
    char* Bb = (char*)Bs;

    const int tid = threadIdx.x;
    const int lane = tid & 63;
    const int wid = tid >> 6;
    const int wm = (wid >> 1) * 64;
    const int wn = (wid & 1) * 64;

    const int* mylist = lists + e * N_TOK + m0;
    const float* lwp = lw + e * N_TOK + m0;

    const int srow = tid >> 4;
    const int scol = (tid & 15) << 2;
    const int swzW = (srow & 7) << 4;

    const float* xptr[8];
#pragma unroll
    for (int p = 0; p < 8; ++p) {
        int r = p * 16 + srow;
        int tok = (m0 + r < M) ? mylist[r] : mylist[0];
        xptr[p] = X + (size_t)tok * DIM_IN + scol;
    }
    const float* wptr = W + ((size_t)e * DIM_OUT + col0 + srow) * DIM_IN + scol;

    f32x4_t acc[4][4];
#pragma unroll
    for (int m = 0; m < 4; ++m)
#pragma unroll
        for (int n = 0; n < 4; ++n)
            acc[m][n] = (f32x4_t)(0.0f);

    for (int k0 = 0; k0 < DIM_IN; k0 += 64) {
#pragma unroll
        for (int p = 0; p < 8; ++p) {
            int r = p * 16 + srow;
            unsigned byteoff = (unsigned)(r * 128 + scol * 2) ^ swzW;
            float4 va = *(const float4*)(xptr[p] + k0);
            s16x4_t ha; ha[0] = f2bf(va.x); ha[1] = f2bf(va.y); ha[2] = f2bf(va.z); ha[3] = f2bf(va.w);
            *(s16x4_t*)(Ab + byteoff) = ha;
            float4 vb = *(const float4*)(wptr + (size_t)p * 16 * DIM_IN + k0);
            s16x4_t hb; hb[0] = f2bf(vb.x); hb[1] = f2bf(vb.y); hb[2] = f2bf(vb.z); hb[3] = f2bf(vb.w);
            *(s16x4_t*)(Bb + byteoff) = hb;
        }
        __syncthreads();

#pragma unroll
        for (int kk = 0; kk < 2; ++kk) {
            const int kb = (kk << 6) + ((lane >> 4) << 4);
            bf16x8_t af[4], bfr[4];
#pragma unroll
            for (int m = 0; m < 4; ++m) {
                int r = wm + (m << 4) + (lane & 15);
                unsigned byteoff = (unsigned)(r * 128 + kb) ^ ((unsigned)(r & 7) << 4);
                af[m] = *(const bf16x8_t*)(Ab + byteoff);
            }
#pragma unroll
            for (int n = 0; n < 4; ++n) {
                int r = wn + (n << 4) + (lane & 15);
                unsigned byteoff = (unsigned)(r * 128 + kb) ^ ((unsigned)(r & 7) << 4);
                bfr[n] = *(const bf16x8_t*)(Bb + byteoff);
            }
#pragma unroll
            for (int m = 0; m < 4; ++m)
#pragma unroll
                for (int n = 0; n < 4; ++n)
                    acc[m][n] = __builtin_amdgcn_mfma_f32_16x16x32_bf16(af[m], bfr[n], acc[m][n], 0, 0, 0);
        }
        __syncthreads();
    }

    const int cl = lane & 15;
    const int rq = (lane >> 4) << 2;
    float biasv[4];
#pragma unroll
    for (int n = 0; n < 4; ++n) biasv[n] = bias[e * DIM_OUT + col0 + wn + n * 16 + cl];
#pragma unroll
    for (int m = 0; m < 4; ++m) {
#pragma unroll
        for (int j = 0; j < 4; ++j) {
            int row = wm + (m << 4) + rq + j;
            if (m0 + row < M) {
                int tok = mylist[row];
                float wgt = lwp[row];
                float* yrow = Y + (size_t)tok * DIM_OUT + col0 + wn;
#pragma unroll
                for (int n = 0; n < 4; ++n)
                    atomicAdd(yrow + n * 16 + cl, wgt * (acc[m][n][j] + biasv[n]));
            }
        }
    }
}

extern "C" void kernel_launch(void* const* d_in, const int* in_sizes, int n_in,
                              void* d_out, int out_size, void* d_ws, size_t ws_size,
                              hipStream_t stream) {
    const float* X = (const float*)d_in[0];
    const float* G = (const float*)d_in[1];
    const float* W = (const float*)d_in[2];
    const float* b = (const float*)d_in[3];
    float* Y = (float*)d_out;

    char* ws = (char*)d_ws;
    int*   counts = (int*)ws;                       // 32 B
    int*   slotA  = (int*)(ws + 256);               // 32 KiB
    int*   slotB  = (int*)(ws + 256 + 32768);       // 32 KiB
    float* wA     = (float*)(ws + 256 + 65536);     // 32 KiB
    float* wB     = (float*)(ws + 256 + 98304);     // 32 KiB
    int*   lists  = (int*)(ws + 256 + 131072);      // 256 KiB
    float* lw     = (float*)(ws + 256 + 131072 + 262144);  // 256 KiB
    size_t o_Xb   = 256 + 131072 + 2 * 262144;
    unsigned short* Xb = (unsigned short*)(ws + o_Xb);
    size_t o_Wb   = o_Xb + (size_t)NX_ELEMS * 2;
    unsigned short* Wb = (unsigned short*)(ws + o_Wb);
    size_t o_scr  = o_Wb + (size_t)NW_ELEMS * 2;
    unsigned short* scratch = (unsigned short*)(ws + o_scr);
    const size_t ws_need_mid  = o_scr;                                    // ~96.6 MiB
    const size_t ws_need_full = o_scr + (size_t)2 * N_TOK * DIM_OUT * 2;  // ~160.6 MiB (bf16 scratch)

    const bool use_scratch = (ws_size >= ws_need_full);
    const bool use_bf16    = (ws_size >= ws_need_mid);

    if (use_bf16) {
        if (use_scratch) {
            hipMemsetAsync(counts, 0, 64, stream);
        } else {
            moe_zero_kernel<<<2048, 256, 0, stream>>>((float4*)Y, out_size / 16, counts);
        }
        moe_gate_cvt_kernel<<<2048, 256, 0, stream>>>(G, X, W, counts, lists, lw,
                                                      slotA, slotB, wA, wB, Xb, Wb);
        dim3 grid(DIM_OUT / BN, N_TOK / BM, N_EXP);
        moe_gemm_bf16<<<grid, 512, 0, stream>>>(Xb, Wb, b, counts, lists, lw,
                                                use_scratch ? scratch : nullptr, Y);
        if (use_scratch) {
            moe_combine_kernel<<<N_TOK, 256, 0, stream>>>(scratch, counts, slotA, slotB,
                                                          wA, wB, Y);
        }
    } else {
        moe_zero_kernel<<<2048, 256, 0, stream>>>((float4*)Y, out_size / 16, counts);
        moe_gate_kernel<<<(N_TOK + 255) / 256, 256, 0, stream>>>(G, counts, lists, lw,
                                                                 slotA, slotB, wA, wB);
        dim3 grid(DIM_OUT / 128, N_TOK / 128, N_EXP);
        moe_gemm_f32<<<grid, 256, 0, stream>>>(X, W, b, counts, lists, lw, Y);
    }
}